// Round 1
// baseline (63.969 us; speedup 1.0000x reference)
//
#include <hip/hip_runtime.h>

// KAN activation: out[b,o,i] = sum_t B_t(x[b,i]) * coef[o,i,t]
// B=2048, IN=OUT=64, 15 knots (uniform), order k=3, 11 basis funcs.
// Bases depend only on (b,i): compute once per pair, stage in LDS,
// reuse coef in registers across a 16-row batch tile.

#define BATCH    2048
#define IN_DIM   64
#define OUT_DIM  64
#define NKNOTS   15   // G + 2k + 1
#define NB0      14   // order-0 bases
#define NCOEF    11   // G + k
#define B_TILE   16
#define O_TILE   4
#define LDS_STR  13   // odd stride -> conflict-free

__global__ __launch_bounds__(256) void kan_kernel(
    const float* __restrict__ x,     // (2048, 64)
    const float* __restrict__ grid,  // (64, 64, 15) broadcast knots
    const float* __restrict__ coef,  // (64, 64, 11)
    float* __restrict__ out)         // (2048, 64, 64)
{
    __shared__ float lds[B_TILE * IN_DIM * LDS_STR];  // 53 KiB

    const int tid    = threadIdx.x;
    const int o_tile = blockIdx.x & (OUT_DIM / O_TILE - 1);  // 16 o-tiles
    const int b_tile = blockIdx.x >> 4;
    const int b0     = b_tile * B_TILE;

    // Knots are identical for every (o,i); read the first row.
    float g[NKNOTS];
    #pragma unroll
    for (int t = 0; t < NKNOTS; ++t) g[t] = grid[t];

    // ---- Phase 1: Cox-de Boor for B_TILE*64 (b,i) pairs, 4 per thread ----
    #pragma unroll
    for (int q = 0; q < (B_TILE * IN_DIM) / 256; ++q) {
        const int p  = tid + q * 256;
        const int bb = p >> 6;
        const int i  = p & 63;
        const float xv = x[(size_t)(b0 + bb) * IN_DIM + i];

        float bas[NB0];
        #pragma unroll
        for (int t = 0; t < NB0; ++t)
            bas[t] = (xv >= g[t] && xv < g[t + 1]) ? 1.0f : 0.0f;

        #pragma unroll
        for (int j = 1; j <= 3; ++j) {
            #pragma unroll
            for (int t = 0; t < NB0 - 3; ++t) {     // max bound; guard below
                if (t < NB0 - j) {
                    float left  = (xv - g[t])       / (g[t + j]     - g[t]);
                    float right = (g[t + j + 1] - xv) / (g[t + j + 1] - g[t + 1]);
                    bas[t] = left * bas[t] + right * bas[t + 1];
                }
            }
            // handle the tail indices t = NB0-3 .. NB0-j-1 for j<3
            #pragma unroll
            for (int t = NB0 - 3; t < NB0 - 1; ++t) {
                if (t < NB0 - j) {
                    float left  = (xv - g[t])       / (g[t + j]     - g[t]);
                    float right = (g[t + j + 1] - xv) / (g[t + j + 1] - g[t + 1]);
                    bas[t] = left * bas[t] + right * bas[t + 1];
                }
            }
        }

        float* dst = &lds[p * LDS_STR];
        #pragma unroll
        for (int t = 0; t < NCOEF; ++t) dst[t] = bas[t];
    }
    __syncthreads();

    // ---- Phase 2: each thread owns (o, i), iterates the batch tile ----
    const int i  = tid & 63;
    const int oo = tid >> 6;               // 0..3
    const int o  = o_tile * O_TILE + oo;

    float c[NCOEF];
    const float* cp = &coef[((size_t)o * IN_DIM + i) * NCOEF];
    #pragma unroll
    for (int t = 0; t < NCOEF; ++t) c[t] = cp[t];

    #pragma unroll
    for (int bb = 0; bb < B_TILE; ++bb) {
        const float* bs = &lds[(bb * IN_DIM + i) * LDS_STR];
        float acc = 0.0f;
        #pragma unroll
        for (int t = 0; t < NCOEF; ++t) acc += bs[t] * c[t];
        out[(size_t)(b0 + bb) * (OUT_DIM * IN_DIM) + o * IN_DIM + i] = acc;
    }
}

extern "C" void kernel_launch(void* const* d_in, const int* in_sizes, int n_in,
                              void* d_out, int out_size, void* d_ws, size_t ws_size,
                              hipStream_t stream) {
    const float* x    = (const float*)d_in[0];
    const float* grid = (const float*)d_in[1];
    const float* coef = (const float*)d_in[2];
    float* out = (float*)d_out;

    const int nblocks = (BATCH / B_TILE) * (OUT_DIM / O_TILE);  // 2048
    kan_kernel<<<nblocks, 256, 0, stream>>>(x, grid, coef, out);
}

// Round 2
// 14.664 us; speedup vs baseline: 4.3623x; 4.3623x over previous
//
#include <hip/hip_runtime.h>

// KAN activation: out[b,o,i] = sum_t B_t(x[b,i]) * coef[o,i,t]
// B=2048, IN=OUT=64, uniform knots (15), order k=3, 11 basis funcs.
//
// Key insight: the grid is UNIFORM -> cubic B-spline has a closed form.
// Only 4 consecutive bases are nonzero; weights are cubic polynomials of
// the fractional cell position. No divisions, no Cox-de Boor recursion.
//
// Phase 1: per (b,i) pair compute 4 weights analytically, scatter into a
//          dense 12-slot row stored as 3 float4 "planes" in LDS
//          (plane[r][pair] -> per-lane contiguous float4 reads, conflict-free).
// Phase 2: thread owns (i, 4 consecutive o); 44 coef values in registers;
//          per batch row 3x ds_read_b128 shared across 4 outputs.

#define BATCH    2048
#define IN_DIM   64
#define OUT_DIM  64
#define NCOEF    11     // G + k
#define B_TILE   8
#define O_TILE   16     // per block (4 groups x 4 o each)
#define NPAIR    (B_TILE * IN_DIM)        // 512
#define PLANE    (NPAIR * 4)              // floats per plane

__global__ __launch_bounds__(256) void kan_kernel(
    const float* __restrict__ x,     // (2048, 64)
    const float* __restrict__ grid,  // (64, 64, 15) broadcast uniform knots
    const float* __restrict__ coef,  // (64, 64, 11)
    float* __restrict__ out)         // (2048, 64, 64)
{
    __shared__ float lds[3 * PLANE];  // 24 KiB

    const int tid    = threadIdx.x;
    const int o_tile = blockIdx.x & 3;        // 4 o-tiles of 16
    const int b_tile = blockIdx.x >> 2;       // 256 b-tiles of 8
    const int b0     = b_tile * B_TILE;

    const float g0    = grid[0];
    const float h     = grid[1] - g0;         // 0.25
    const float inv_h = 1.0f / h;             // hoisted; 1 divide per thread

    // ---- Phase 1: analytic cubic B-spline weights, 2 pairs per thread ----
    #pragma unroll
    for (int q = 0; q < NPAIR / 256; ++q) {
        const int p  = tid + q * 256;
        const int bb = p >> 6;
        const int i  = p & 63;
        const float xv = x[(size_t)(b0 + bb) * IN_DIM + i];

        // zero the dense row (3 float4 planes)
        const float4 z = make_float4(0.f, 0.f, 0.f, 0.f);
        *(float4*)&lds[0 * PLANE + p * 4] = z;
        *(float4*)&lds[1 * PLANE + p * 4] = z;
        *(float4*)&lds[2 * PLANE + p * 4] = z;

        const float pos = (xv - g0) * inv_h;   // cell position in [0,14)
        if (pos >= 0.0f && pos < 14.0f) {
            const int   m  = (int)pos;         // knot interval index
            const float t  = pos - (float)m;   // fractional position
            const float t2 = t * t;
            const float t3 = t2 * t;
            const float s  = 1.0f - t;
            const float w0 = s * s * s * (1.0f / 6.0f);
            const float w1 = (3.0f * t3 - 6.0f * t2 + 4.0f) * (1.0f / 6.0f);
            const float w2 = (-3.0f * t3 + 3.0f * t2 + 3.0f * t + 1.0f) * (1.0f / 6.0f);
            const float w3 = t3 * (1.0f / 6.0f);

            const int mb = m - 3;              // dense index of w0
            int idx;
            idx = mb + 0; if ((unsigned)idx < NCOEF) lds[(idx >> 2) * PLANE + p * 4 + (idx & 3)] = w0;
            idx = mb + 1; if ((unsigned)idx < NCOEF) lds[(idx >> 2) * PLANE + p * 4 + (idx & 3)] = w1;
            idx = mb + 2; if ((unsigned)idx < NCOEF) lds[(idx >> 2) * PLANE + p * 4 + (idx & 3)] = w2;
            idx = mb + 3; if ((unsigned)idx < NCOEF) lds[(idx >> 2) * PLANE + p * 4 + (idx & 3)] = w3;
        }
    }
    __syncthreads();

    // ---- Phase 2: thread owns (i, 4 consecutive o); coef in registers ----
    const int i   = tid & 63;
    const int grp = tid >> 6;                  // 0..3
    const int o   = o_tile * O_TILE + grp * 4;

    // 44 coef values in registers
    float c[4][NCOEF];
    const float* cp = &coef[((size_t)o * IN_DIM + i) * NCOEF];
    #pragma unroll
    for (int oo = 0; oo < 4; ++oo)
        #pragma unroll
        for (int t = 0; t < NCOEF; ++t)
            c[oo][t] = cp[(size_t)oo * IN_DIM * NCOEF + t];

    #pragma unroll
    for (int bb = 0; bb < B_TILE; ++bb) {
        const int p = bb * IN_DIM + i;
        const float4 v0 = *(const float4*)&lds[0 * PLANE + p * 4];
        const float4 v1 = *(const float4*)&lds[1 * PLANE + p * 4];
        const float4 v2 = *(const float4*)&lds[2 * PLANE + p * 4];

        float* op = &out[(size_t)(b0 + bb) * (OUT_DIM * IN_DIM) + o * IN_DIM + i];
        #pragma unroll
        for (int oo = 0; oo < 4; ++oo) {
            float acc;
            acc  = v0.x * c[oo][0] + v0.y * c[oo][1] + v0.z * c[oo][2] + v0.w * c[oo][3];
            acc += v1.x * c[oo][4] + v1.y * c[oo][5] + v1.z * c[oo][6] + v1.w * c[oo][7];
            acc += v2.x * c[oo][8] + v2.y * c[oo][9] + v2.z * c[oo][10];
            op[oo * IN_DIM] = acc;
        }
    }
}

extern "C" void kernel_launch(void* const* d_in, const int* in_sizes, int n_in,
                              void* d_out, int out_size, void* d_ws, size_t ws_size,
                              hipStream_t stream) {
    const float* x    = (const float*)d_in[0];
    const float* grid = (const float*)d_in[1];
    const float* coef = (const float*)d_in[2];
    float* out = (float*)d_out;

    const int nblocks = (BATCH / B_TILE) * (OUT_DIM / O_TILE);  // 1024
    kan_kernel<<<nblocks, 256, 0, stream>>>(x, grid, coef, out);
}